// Round 1
// baseline (4648.306 us; speedup 1.0000x reference)
//
#include <hip/hip_runtime.h>
#include <hip/hip_bf16.h>
#include <math.h>

// Problem constants (match reference)
#define B_   128
#define L_   31
#define T_   32
#define E_   512
#define TAG_ 512
#define H_   1024
#define G_   4096   // 4*H
#define V_   30000

// ---------------------------------------------------------------------------
// bsum[g] = b_ih[g] + b_hh[g]
__global__ __launch_bounds__(256) void bsum_kernel(
    const float* __restrict__ b_ih, const float* __restrict__ b_hh,
    float* __restrict__ bsum)
{
    int g = blockIdx.x * 256 + threadIdx.x;
    if (g < G_) bsum[g] = b_ih[g] + b_hh[g];
}

// ---------------------------------------------------------------------------
// X[b*T + t][e] = (t==0) ? features[b][e] : W_embed[captions[b][t-1]][e]
// one float4 per thread
__global__ __launch_bounds__(256) void prep_x_kernel(
    const float* __restrict__ features, const int* __restrict__ captions,
    const float* __restrict__ W_embed, float* __restrict__ X)
{
    int idx = blockIdx.x * 256 + threadIdx.x;        // over B*T*E/4 = 524288
    if (idx >= B_ * T_ * E_ / 4) return;
    int e4 = idx & (E_ / 4 - 1);                     // 0..127
    int m  = idx >> 7;                               // 0..4095 (b*T + t)
    int b = m >> 5, t = m & 31;
    const float* src = (t == 0)
        ? (features + (size_t)b * E_)
        : (W_embed + (size_t)captions[b * L_ + (t - 1)] * E_);
    ((float4*)X)[idx] = *(const float4*)(src + e4 * 4);
}

// ---------------------------------------------------------------------------
// Generic NT SGEMM: C[m,n] = sum_k A[amap?amap[m]:m, k] * B[n, k]
//                          (+ add[(m/addDiv)*ldadd + n]) (+ bias[n])
// Tile 64x64, 256 threads, 4x4 per thread, K-chunk 16.
__global__ __launch_bounds__(256) void sgemm_nt(
    const float* __restrict__ A, int lda,
    const float* __restrict__ Bm, int ldb,
    float* __restrict__ C, int ldc,
    int M, int N, int K,
    const int* __restrict__ amap,
    const float* __restrict__ add, int ldadd, int addDiv,
    const float* __restrict__ bias)
{
    __shared__ float As[16][68];
    __shared__ float Bs[16][68];
    const int tid = threadIdx.x;
    const int tx = tid & 15, ty = tid >> 4;
    const int m0 = blockIdx.y * 64, n0 = blockIdx.x * 64;
    const int lrow = tid >> 2;          // 0..63
    const int lk   = (tid & 3) << 2;    // 0,4,8,12

    const int am = m0 + lrow;
    const float* arow = nullptr;
    if (am < M) {
        int ar = amap ? amap[am] : am;
        arow = A + (size_t)ar * lda + lk;
    }
    const int bn = n0 + lrow;
    const float* brow = (bn < N) ? (Bm + (size_t)bn * ldb + lk) : nullptr;

    float acc[4][4] = {};

    for (int k0 = 0; k0 < K; k0 += 16) {
        float4 av = arow ? *(const float4*)(arow + k0) : make_float4(0.f,0.f,0.f,0.f);
        float4 bv = brow ? *(const float4*)(brow + k0) : make_float4(0.f,0.f,0.f,0.f);
        __syncthreads();   // previous iter done reading LDS
        As[lk+0][lrow] = av.x; As[lk+1][lrow] = av.y;
        As[lk+2][lrow] = av.z; As[lk+3][lrow] = av.w;
        Bs[lk+0][lrow] = bv.x; Bs[lk+1][lrow] = bv.y;
        Bs[lk+2][lrow] = bv.z; Bs[lk+3][lrow] = bv.w;
        __syncthreads();
        #pragma unroll
        for (int k = 0; k < 16; ++k) {
            const float4 a4 = *(const float4*)&As[k][ty << 2];
            const float4 b4 = *(const float4*)&Bs[k][tx << 2];
            acc[0][0] += a4.x*b4.x; acc[0][1] += a4.x*b4.y; acc[0][2] += a4.x*b4.z; acc[0][3] += a4.x*b4.w;
            acc[1][0] += a4.y*b4.x; acc[1][1] += a4.y*b4.y; acc[1][2] += a4.y*b4.z; acc[1][3] += a4.y*b4.w;
            acc[2][0] += a4.z*b4.x; acc[2][1] += a4.z*b4.y; acc[2][2] += a4.z*b4.z; acc[2][3] += a4.z*b4.w;
            acc[3][0] += a4.w*b4.x; acc[3][1] += a4.w*b4.y; acc[3][2] += a4.w*b4.z; acc[3][3] += a4.w*b4.w;
        }
    }

    const int n = n0 + (tx << 2);
    #pragma unroll
    for (int i = 0; i < 4; ++i) {
        const int m = m0 + (ty << 2) + i;
        if (m >= M) continue;
        float rv[4] = {acc[i][0], acc[i][1], acc[i][2], acc[i][3]};
        if (n + 3 < N) {
            if (add) {
                const float* ar = add + (size_t)(m / addDiv) * ldadd + n;
                rv[0] += ar[0]; rv[1] += ar[1]; rv[2] += ar[2]; rv[3] += ar[3];
            }
            if (bias) {
                rv[0] += bias[n+0]; rv[1] += bias[n+1];
                rv[2] += bias[n+2]; rv[3] += bias[n+3];
            }
            *(float4*)(C + (size_t)m * ldc + n) =
                make_float4(rv[0], rv[1], rv[2], rv[3]);
        } else {
            for (int j = 0; j < 4; ++j) {
                if (n + j < N) {
                    float v = rv[j];
                    if (add)  v += add[(size_t)(m / addDiv) * ldadd + n + j];
                    if (bias) v += bias[n + j];
                    C[(size_t)m * ldc + n + j] = v;
                }
            }
        }
    }
}

// ---------------------------------------------------------------------------
// LSTM cell elementwise: gates[b, 4H] -> h,c update; h stored to hid[b*T+t]
__global__ __launch_bounds__(256) void lstm_cell_kernel(
    const float* __restrict__ gates, float* __restrict__ h,
    float* __restrict__ c, float* __restrict__ hid, int t)
{
    int idx = blockIdx.x * 256 + threadIdx.x;     // 0 .. B*H-1
    if (idx >= B_ * H_) return;
    int b = idx >> 10, j = idx & (H_ - 1);
    const float* gr = gates + (size_t)b * G_;
    float iv = 1.0f / (1.0f + expf(-gr[j]));
    float fv = 1.0f / (1.0f + expf(-gr[j + H_]));
    float gv = tanhf(gr[j + 2 * H_]);
    float ov = 1.0f / (1.0f + expf(-gr[j + 3 * H_]));
    float cv = fv * c[idx] + iv * gv;
    float hv = ov * tanhf(cv);
    c[idx] = cv;
    h[idx] = hv;
    hid[((size_t)b * T_ + t) * H_ + j] = hv;
}

// ---------------------------------------------------------------------------
// amap[r] = b*T + t for packed row r (reference pack order).
// n_t = #(lengths > t) (order-invariant count); rows r = off_t + b, b<n_t.
__global__ __launch_bounds__(64) void rowmap_kernel(
    const int* __restrict__ lengths, int* __restrict__ amap)
{
    __shared__ int nt[T_];
    __shared__ int off[T_];
    int tid = threadIdx.x;
    if (tid < T_) {
        int cnt = 0;
        for (int b = 0; b < B_; ++b) cnt += (lengths[b] > tid) ? 1 : 0;
        nt[tid] = cnt;
    }
    __syncthreads();
    if (tid == 0) {
        int s = 0;
        for (int t = 0; t < T_; ++t) { off[t] = s; s += nt[t]; }
    }
    __syncthreads();
    if (tid < T_) {
        int o = off[tid];
        for (int b = 0; b < nt[tid]; ++b) amap[o + b] = b * T_ + tid;
    }
}

// ---------------------------------------------------------------------------
extern "C" void kernel_launch(void* const* d_in, const int* in_sizes, int n_in,
                              void* d_out, int out_size, void* d_ws, size_t ws_size,
                              hipStream_t stream) {
    const float* features = (const float*)d_in[0];
    const float* tags     = (const float*)d_in[1];
    const int*   captions = (const int*)d_in[2];
    const int*   lengths  = (const int*)d_in[3];
    const float* W_embed  = (const float*)d_in[4];
    const float* W_ih     = (const float*)d_in[5];
    const float* W_hh     = (const float*)d_in[6];
    const float* b_ih     = (const float*)d_in[7];
    const float* b_hh     = (const float*)d_in[8];
    const float* W_lin    = (const float*)d_in[9];
    const float* b_lin    = (const float*)d_in[10];
    float* out = (float*)d_out;
    const int R = out_size / V_;   // packed rows = sum(lengths)

    // workspace layout
    char* w = (char*)d_ws;
    size_t off = 0;
    auto alloc = [&](size_t bytes) -> void* {
        void* p = w + off;
        off = (off + bytes + 255) & ~(size_t)255;
        return p;
    };
    float* X    = (float*)alloc(sizeof(float) * (size_t)B_ * T_ * E_);   //  8 MB
    float* gtag = (float*)alloc(sizeof(float) * (size_t)B_ * G_);        //  2 MB
    float* gx   = (float*)alloc(sizeof(float) * (size_t)B_ * T_ * G_);   // 64 MB
    float* hid  = (float*)alloc(sizeof(float) * (size_t)B_ * T_ * H_);   // 16 MB
    float* hc   = (float*)alloc(sizeof(float) * (size_t)2 * B_ * H_);    //  1 MB
    float* hbuf = hc;
    float* cbuf = hc + (size_t)B_ * H_;
    float* gates = (float*)alloc(sizeof(float) * (size_t)B_ * G_);       //  2 MB
    float* bsum  = (float*)alloc(sizeof(float) * G_);
    int*   amap  = (int*)alloc(sizeof(int) * B_ * T_);

    // 1) bias sum
    bsum_kernel<<<dim3((G_ + 255) / 256), dim3(256), 0, stream>>>(b_ih, b_hh, bsum);

    // 2) gather X = [features ; embeddings]
    prep_x_kernel<<<dim3(B_ * T_ * E_ / 4 / 256), dim3(256), 0, stream>>>(
        features, captions, W_embed, X);

    // 3) gtag = tags @ W_ih[:,512:]^T + (b_ih + b_hh)     [128 x 4096]
    sgemm_nt<<<dim3(G_ / 64, B_ / 64), dim3(256), 0, stream>>>(
        tags, TAG_, W_ih + E_, E_ + TAG_, gtag, G_,
        B_, G_, TAG_, nullptr, nullptr, 0, 1, bsum);

    // 4) gx = X @ W_ih[:,:512]^T + gtag[b]                [4096 x 4096]
    sgemm_nt<<<dim3(G_ / 64, (B_ * T_) / 64), dim3(256), 0, stream>>>(
        X, E_, W_ih, E_ + TAG_, gx, G_,
        B_ * T_, G_, E_, nullptr, gtag, G_, T_, nullptr);

    // 5) h0 = c0 = 0
    hipMemsetAsync(hc, 0, sizeof(float) * (size_t)2 * B_ * H_, stream);

    // 6) 32 sequential LSTM steps
    for (int t = 0; t < T_; ++t) {
        // gates = h @ W_hh^T + gx[:, t, :]                [128 x 4096]
        sgemm_nt<<<dim3(G_ / 64, B_ / 64), dim3(256), 0, stream>>>(
            hbuf, H_, W_hh, H_, gates, G_,
            B_, G_, H_, nullptr, gx + (size_t)t * G_, T_ * G_, 1, nullptr);
        lstm_cell_kernel<<<dim3((B_ * H_ + 255) / 256), dim3(256), 0, stream>>>(
            gates, hbuf, cbuf, hid, t);
    }

    // 7) pack row map
    rowmap_kernel<<<dim3(1), dim3(64), 0, stream>>>(lengths, amap);

    // 8) out = packed_h @ W_lin^T + b_lin                 [R x 30000]
    sgemm_nt<<<dim3((V_ + 63) / 64, (R + 63) / 64), dim3(256), 0, stream>>>(
        hid, H_, W_lin, H_, out, V_,
        R, V_, H_, amap, nullptr, 0, 1, b_lin);
}

// Round 2
// 1377.590 us; speedup vs baseline: 3.3742x; 3.3742x over previous
//
#include <hip/hip_runtime.h>
#include <hip/hip_bf16.h>
#include <math.h>
#include <stdint.h>

#define B_   128
#define L_   31
#define T_   32
#define E_   512
#define TAG_ 512
#define H_   1024
#define G_   4096   // 4*H
#define V_   30000
#define NPAD 30080  // 235*128, padded vocab for 128-wide N tiles

typedef __bf16 bf16x8 __attribute__((ext_vector_type(8)));
typedef float  f32x4  __attribute__((ext_vector_type(4)));

// async global->LDS, 16B per lane; LDS dest is wave-uniform base + lane*16
#define GLL16(gsrc, ldst) \
  __builtin_amdgcn_global_load_lds((__attribute__((address_space(1))) void*)(gsrc), \
                                   (__attribute__((address_space(3))) void*)(ldst), 16, 0, 0)

// ---------------------------------------------------------------------------
__global__ __launch_bounds__(256) void bsum_kernel(
    const float* __restrict__ b_ih, const float* __restrict__ b_hh,
    float* __restrict__ bsum)
{
    int g = blockIdx.x * 256 + threadIdx.x;
    if (g < G_) bsum[g] = b_ih[g] + b_hh[g];
}

// ---------------------------------------------------------------------------
// fp32 -> bf16 bulk convert (4 elems/thread)
__global__ __launch_bounds__(256) void f2b_kernel(
    const float* __restrict__ src, __bf16* __restrict__ dst, int n4)
{
    const int i = blockIdx.x * 256 + threadIdx.x;
    if (i >= n4) return;
    const float4 v = ((const float4*)src)[i];
    union { __bf16 b4[4]; ushort4 u; } o;
    o.b4[0] = (__bf16)v.x; o.b4[1] = (__bf16)v.y;
    o.b4[2] = (__bf16)v.z; o.b4[3] = (__bf16)v.w;
    ((ushort4*)dst)[i] = o.u;
}

// ---------------------------------------------------------------------------
// Xcat[b*T+t][0:512]   = (t==0) ? features[b] : W_embed[captions[b][t-1]]
// Xcat[b*T+t][512:1024]= tags[b]          (bf16)
__global__ __launch_bounds__(256) void xcat_kernel(
    const float* __restrict__ features, const float* __restrict__ tags,
    const int* __restrict__ captions, const float* __restrict__ W_embed,
    __bf16* __restrict__ Xcat)
{
    const int idx = blockIdx.x * 256 + threadIdx.x;   // over B*T*256
    if (idx >= B_ * T_ * 256) return;
    const int c4 = idx & 255;
    const int m  = idx >> 8;        // b*T + t
    const int b = m >> 5, t = m & 31;
    const int col = c4 * 4;
    const float* src;
    if (col < E_)
        src = (t == 0) ? features + (long)b * E_ + col
                       : W_embed + (long)captions[b * L_ + t - 1] * E_ + col;
    else
        src = tags + (long)b * TAG_ + (col - E_);
    const float4 v = *(const float4*)src;
    union { __bf16 b4[4]; ushort4 u; } o;
    o.b4[0] = (__bf16)v.x; o.b4[1] = (__bf16)v.y;
    o.b4[2] = (__bf16)v.z; o.b4[3] = (__bf16)v.w;
    ((ushort4*)Xcat)[idx] = o.u;
}

// ---------------------------------------------------------------------------
// bf16 MFMA GEMM, NT: C[m,n] = sum_k A[amap?amap[m]:m, k] * B[n, k] (+bias[n])
// 128x128 tile, BK=32, 256 threads = 4 waves (2x2 of 64x64), 16x16x32 MFMA.
// Split-K via blockIdx.z: k range [z*K, (z+1)*K), C += z*partStride.
__global__ __launch_bounds__(256) void gemm_bf16(
    const __bf16* __restrict__ A, int lda,
    const __bf16* __restrict__ Bm, int ldb,
    float* __restrict__ C, int ldc, long partStride,
    int M, int Nst, int K,
    const int* __restrict__ amap,
    const float* __restrict__ bias)
{
    __shared__ __attribute__((aligned(16))) __bf16 As[128 * 32];
    __shared__ __attribute__((aligned(16))) __bf16 Bs[128 * 32];

    const int tid  = threadIdx.x;
    const int lane = tid & 63;
    const int w    = tid >> 6;
    const int m0   = blockIdx.y * 128;
    const int n0   = blockIdx.x * 128;
    const int kb   = blockIdx.z * K;
    C += (long)blockIdx.z * partStride;

    // staging: wave w loads A rows [w*16, +16) and [w*16+64, +16), same for B
    const int srow = lane >> 2;           // 0..15 within unit
    const int scol = (lane & 3) * 8;      // element offset (16B per lane)
    int ai0 = m0 + w * 16 + srow;
    int ai1 = ai0 + 64;
    if (amap) { ai0 = amap[ai0]; ai1 = amap[ai1]; }
    const __bf16* ag0 = A + (long)ai0 * lda + kb + scol;
    const __bf16* ag1 = A + (long)ai1 * lda + kb + scol;
    const __bf16* bg0 = Bm + (long)(n0 + w * 16 + srow) * ldb + kb + scol;
    const __bf16* bg1 = bg0 + (long)64 * ldb;
    __bf16* al0 = &As[(w * 16) * 32];
    __bf16* al1 = &As[(w * 16 + 64) * 32];
    __bf16* bl0 = &Bs[(w * 16) * 32];
    __bf16* bl1 = &Bs[(w * 16 + 64) * 32];

    const int wm = (w >> 1) * 64;   // wave origin in tile
    const int wn = (w & 1) * 64;
    const int fr = lane & 15;
    const int kg = lane >> 4;

    f32x4 acc[4][4] = {};

    for (int k0 = 0; k0 < K; k0 += 32) {
        GLL16(ag0 + k0, al0);
        GLL16(ag1 + k0, al1);
        GLL16(bg0 + k0, bl0);
        GLL16(bg1 + k0, bl1);
        __syncthreads();                 // drains vmcnt: tiles ready
        bf16x8 af[4], bf_[4];
        #pragma unroll
        for (int i = 0; i < 4; ++i) {
            af[i]  = *(const bf16x8*)&As[(wm + i * 16 + fr) * 32 + kg * 8];
            bf_[i] = *(const bf16x8*)&Bs[(wn + i * 16 + fr) * 32 + kg * 8];
        }
        #pragma unroll
        for (int i = 0; i < 4; ++i)
            #pragma unroll
            for (int j = 0; j < 4; ++j)
                acc[i][j] = __builtin_amdgcn_mfma_f32_16x16x32_bf16(
                    af[i], bf_[j], acc[i][j], 0, 0, 0);
        __syncthreads();                 // all waves done reading LDS
    }

    // C/D layout: col = lane&15, row = (lane>>4)*4 + reg  [m89/m91 verified]
    #pragma unroll
    for (int i = 0; i < 4; ++i) {
        const int mloc = wm + i * 16 + kg * 4;
        #pragma unroll
        for (int j = 0; j < 4; ++j) {
            const int n = n0 + wn + j * 16 + fr;
            if (n >= Nst) continue;
            const float bv = bias ? bias[n] : 0.0f;
            #pragma unroll
            for (int r = 0; r < 4; ++r) {
                const int m = m0 + mloc + r;
                if (m < M)
                    C[(long)m * ldc + n] = acc[i][j][r] + bv;
            }
        }
    }
}

// ---------------------------------------------------------------------------
// LSTM cell: gates = gx[b,t] + sum_z part[z]; fp32 nonlinearity; h -> bf16
__global__ __launch_bounds__(256) void cell_kernel(
    const float* __restrict__ part,    // [4][B][4096]
    const float* __restrict__ gxt,     // gx + t*G, rows stride T*G
    float* __restrict__ cbuf,
    __bf16* __restrict__ hcur,
    __bf16* __restrict__ hid, int t)
{
    const int idx = blockIdx.x * 256 + threadIdx.x;   // B*H exactly
    const int b = idx >> 10, j = idx & (H_ - 1);
    const long PS = (long)B_ * G_;
    float ga[4];
    #pragma unroll
    for (int q = 0; q < 4; ++q) {
        const long go = (long)b * G_ + q * H_ + j;
        float v = gxt[(long)b * (T_ * G_) + q * H_ + j];
        v += part[go] + part[go + PS] + part[go + 2 * PS] + part[go + 3 * PS];
        ga[q] = v;
    }
    const float iv = 1.f / (1.f + expf(-ga[0]));
    const float fv = 1.f / (1.f + expf(-ga[1]));
    const float gv = tanhf(ga[2]);
    const float ov = 1.f / (1.f + expf(-ga[3]));
    const float c  = fv * cbuf[idx] + iv * gv;
    const float h  = ov * tanhf(c);
    cbuf[idx] = c;
    const __bf16 hb = (__bf16)h;
    hcur[idx] = hb;
    hid[((long)b * T_ + t) * H_ + j] = hb;
}

// ---------------------------------------------------------------------------
// amap[r] = b*T + t in reference pack order; pad [R, padM) with 0
__global__ __launch_bounds__(64) void rowmap_kernel(
    const int* __restrict__ lengths, int* __restrict__ amap, int padM)
{
    __shared__ int nt[T_], off[T_];
    const int tid = threadIdx.x;
    for (int r = tid; r < padM; r += 64) amap[r] = 0;
    if (tid < T_) {
        int cnt = 0;
        for (int b = 0; b < B_; ++b) cnt += (lengths[b] > tid) ? 1 : 0;
        nt[tid] = cnt;
    }
    __syncthreads();
    if (tid == 0) {
        int s = 0;
        for (int t = 0; t < T_; ++t) { off[t] = s; s += nt[t]; }
    }
    __syncthreads();
    if (tid < T_) {
        const int o = off[tid];
        for (int b = 0; b < nt[tid]; ++b) amap[o + b] = b * T_ + tid;
    }
}

// ---------------------------------------------------------------------------
extern "C" void kernel_launch(void* const* d_in, const int* in_sizes, int n_in,
                              void* d_out, int out_size, void* d_ws, size_t ws_size,
                              hipStream_t stream)
{
    const float* features = (const float*)d_in[0];
    const float* tags     = (const float*)d_in[1];
    const int*   captions = (const int*)d_in[2];
    const int*   lengths  = (const int*)d_in[3];
    const float* W_embed  = (const float*)d_in[4];
    const float* W_ih     = (const float*)d_in[5];
    const float* W_hh     = (const float*)d_in[6];
    const float* b_ih     = (const float*)d_in[7];
    const float* b_hh     = (const float*)d_in[8];
    const float* W_lin    = (const float*)d_in[9];
    const float* b_lin    = (const float*)d_in[10];
    float* out = (float*)d_out;
    const int R     = out_size / V_;
    const int gridY = (R + 127) / 128;
    const int padM  = gridY * 128;

    // workspace layout (peak ~105 MB):
    // [0,8M)  Xcat bf16      -- dead after gx GEMM
    // [8,16M) Wihb bf16      -- dead after gx GEMM
    // [16,80M) gx fp32       -- dead after last cell
    // [0,61.6M) Wlinb bf16   -- OVERLAYS the above, built after recurrence
    // [80M..) persistent: Whhb, hid, hcur, cbuf, part, bsum, amap
    char* w = (char*)d_ws;
    __bf16* Xcat  = (__bf16*)(w);
    __bf16* Wihb  = (__bf16*)(w + (8ll << 20));
    float*  gx    = (float*) (w + (16ll << 20));
    __bf16* Wlinb = (__bf16*)(w);
    char* p = w + (80ll << 20);
    __bf16* Whhb = (__bf16*)p; p += (size_t)G_ * H_ * 2;
    __bf16* hid  = (__bf16*)p; p += (size_t)B_ * T_ * H_ * 2;
    __bf16* hcur = (__bf16*)p; p += (size_t)B_ * H_ * 2;
    float*  cbuf = (float*) p; p += (size_t)B_ * H_ * 4;
    float*  part = (float*) p; p += (size_t)4 * B_ * G_ * 4;
    float*  bsum = (float*) p; p += (size_t)G_ * 4;
    int*    amap = (int*)   p; p += (size_t)4096 * 4;

    const dim3 blk(256);

    bsum_kernel<<<G_ / 256, blk, 0, stream>>>(b_ih, b_hh, bsum);
    xcat_kernel<<<(B_ * T_ * 256) / 256, blk, 0, stream>>>(
        features, tags, captions, W_embed, Xcat);
    f2b_kernel<<<(G_ * (E_ + TAG_) / 4) / 256, blk, 0, stream>>>(
        W_ih, Wihb, G_ * (E_ + TAG_) / 4);
    f2b_kernel<<<(G_ * H_ / 4) / 256, blk, 0, stream>>>(W_hh, Whhb, G_ * H_ / 4);

    // gx = Xcat @ W_ih^T + (b_ih + b_hh)          [4096 x 4096], K=1024
    gemm_bf16<<<dim3(G_ / 128, (B_ * T_) / 128, 1), blk, 0, stream>>>(
        Xcat, E_ + TAG_, Wihb, E_ + TAG_, gx, G_, 0,
        B_ * T_, G_, E_ + TAG_, nullptr, bsum);

    hipMemsetAsync(hcur, 0, (size_t)B_ * H_ * 2, stream);
    hipMemsetAsync(cbuf, 0, (size_t)B_ * H_ * 4, stream);
    rowmap_kernel<<<1, 64, 0, stream>>>(lengths, amap, padM);

    // 32 sequential steps: part[z] = h @ W_hh[:, z*256:(z+1)*256]^T ; cell
    for (int t = 0; t < T_; ++t) {
        gemm_bf16<<<dim3(G_ / 128, 1, 4), blk, 0, stream>>>(
            hcur, H_, Whhb, H_, part, G_, (long)B_ * G_,
            B_, G_, H_ / 4, nullptr, nullptr);
        cell_kernel<<<(B_ * H_) / 256, blk, 0, stream>>>(
            part, gx + (size_t)t * G_, cbuf, hcur, hid, t);
    }

    // W_lin -> bf16 (overlays gx region; gx is dead now)
    f2b_kernel<<<(V_ * H_ / 4) / 256, blk, 0, stream>>>(W_lin, Wlinb, V_ * H_ / 4);

    // out = packed_h @ W_lin^T + b_lin            [R x 30000], K=1024
    gemm_bf16<<<dim3(NPAD / 128, gridY, 1), blk, 0, stream>>>(
        hid, H_, Wlinb, H_, out, V_, 0,
        R, V_, H_, amap, b_lin);
}